// Round 4
// baseline (64.711 us; speedup 1.0000x reference)
//
#include <hip/hip_runtime.h>

#define BB 64
#define TT 12
#define NL 2000
#define PP 20
#define CLS 2
#define BIGF 1.0e9f

#define TPB   512                 // 8 waves per block
#define NWAVE 8
#define LPB   500                 // lines per block
#define NBLK  4                   // NL / LPB
#define NSLOT NBLK
#define NBLOCKS (NBLK * BB)       // 256 blocks total

// ws layout (uint32 units), [t][s][b] so final reads coalesce over b:
//   mind2 : [(t*NSLOT + s)*BB + b]      (floats)
//   cmask : [OFF_CM  + s*BB + b]
//   cnt   : [OFF_CNT + s*BB + b]
//   ctr   : [OFF_CTR]  ticket counter, zeroed by a 4-byte memset node
#define OFF_CM  (TT * NSLOT * BB)
#define OFF_CNT (TT * NSLOT * BB + NSLOT * BB)
#define OFF_CTR (TT * NSLOT * BB + 2 * NSLOT * BB)
// total 3585 u32 ~= 14 KB of d_ws

// NOTE: no min-waves arg in __launch_bounds__ — (64,2)/(256,4) made hipcc cap
// VGPRs (128/64) and spill ~50 dwords/thread to scratch (13-68 MB of HBM
// write-back). 512-thread block -> 2 waves/SIMD, VGPR cap 256, live set ~100.
__global__ __launch_bounds__(TPB) void gtmb_fused(
    const float* __restrict__ pred,    // B,T,2
    const float* __restrict__ pts,     // B,N,1,P,2
    const int*   __restrict__ labels,  // B,N
    const float* __restrict__ masks,   // B,T
    unsigned int* __restrict__ ws,
    float* __restrict__ out) {
    const int b    = blockIdx.y;
    const int blk  = blockIdx.x;       // chunk of 500 lines
    const int tid  = threadIdx.x;
    const int lane = tid & 63, wave = tid >> 6;

    __shared__ unsigned short sidx[LPB];
    __shared__ int wcnt[NWAVE];
    __shared__ float sred[NWAVE][TT];
    __shared__ unsigned int scmw[NWAVE];
    __shared__ int slast;
    __shared__ float smf[TT * BB];              // final-stage only
    __shared__ unsigned int scm[BB], shas[BB];  // final-stage only

    // ---- phase 1: ballot compaction of valid lines (8-wave LDS prefix) ----
    const int base = blk * LPB;
    int v0 = 0, v1 = 0, n0 = 0;
    if (tid < LPB / 2) {               // 250 int2 = 500 labels
        n0 = base + 2 * tid;           // base even -> int2-aligned
        int2 lb = *reinterpret_cast<const int2*>(labels + b * NL + n0);
        v0 = (lb.x == CLS);
        v1 = (lb.y == CLS);
    }
    unsigned long long m0 = __ballot(v0);
    unsigned long long m1 = __ballot(v1);
    unsigned long long lt = (1ull << lane) - 1ull;
    if (lane == 0) wcnt[wave] = __popcll(m0) + __popcll(m1);
    __syncthreads();
    int off = 0, cnt = 0;
#pragma unroll
    for (int w2 = 0; w2 < NWAVE; ++w2) {
        int c = wcnt[w2];
        if (w2 < wave) off += c;
        cnt += c;
    }
    const int c0 = __popcll(m0);
    if (v0) sidx[off + __popcll(m0 & lt)]      = (unsigned short)n0;
    if (v1) sidx[off + c0 + __popcll(m1 & lt)] = (unsigned short)(n0 + 1);
    __syncthreads();

    // ---- trajectory (block-uniform, compiler scalarizes) ----
    float ex[TT], ey[TT];
    const float* pb = pred + b * (TT * 2);
#pragma unroll
    for (int t = 0; t < TT; ++t) { ex[t] = pb[2*t]; ey[t] = pb[2*t+1]; }

    float mind2[TT];
#pragma unroll
    for (int t = 0; t < TT; ++t) mind2[t] = BIGF;
    unsigned int cmask = 0;

    // ---- phase 2: dense items, one half-line (10 pts / 10 segs) per item ----
    // nitems = 2*cnt ~ 250+-19 << 512 -> single pass, no 2-round tail.
    const int nitems = 2 * cnt;
    for (int w = tid; w < nitems; w += TPB) {
        const int ln = sidx[w >> 1];
        const int h  = w & 1;
        const float4* lp = reinterpret_cast<const float4*>(
                               pts + (long)(b * NL + ln) * (PP * 2)) + h * 5;
        float4 q0 = lp[0], q1 = lp[1], q2 = lp[2], q3 = lp[3], q4 = lp[4];
        float p10x = q4.z, p10y = q4.w;          // h=1: dup of p9 (degenerate)
        if (h == 0) { float4 q5 = lp[5]; p10x = q5.x; p10y = q5.y; }

        float px[11], py[11];
        px[0]=q0.x; py[0]=q0.y;  px[1]=q0.z; py[1]=q0.w;
        px[2]=q1.x; py[2]=q1.y;  px[3]=q1.z; py[3]=q1.w;
        px[4]=q2.x; py[4]=q2.y;  px[5]=q2.z; py[5]=q2.w;
        px[6]=q3.x; py[6]=q3.y;  px[7]=q3.z; py[7]=q3.w;
        px[8]=q4.x; py[8]=q4.y;  px[9]=q4.z; py[9]=q4.w;
        px[10]=p10x; py[10]=p10y;

        // min distance^2: pts 0..9 (pt 10 is the next half's pt 0)
#pragma unroll
        for (int i = 0; i < 10; ++i) {
#pragma unroll
            for (int t = 0; t < TT; ++t) {
                float dx = px[i] - ex[t];
                float dy = py[i] - ey[t];
                mind2[t] = fminf(mind2[t], fmaf(dx, dx, dy * dy));
            }
        }

        // segment intersection: segs (i,i+1), i=0..9
#pragma unroll
        for (int i = 0; i < 10; ++i) {
            float dx2 = px[i+1] - px[i];
            float dy2 = py[i+1] - py[i];
#pragma unroll
            for (int t = 0; t < TT; ++t) {
                float sx = t ? ex[t-1] : 0.0f;
                float sy = t ? ey[t-1] : 0.0f;
                float dxt = ex[t] - sx;
                float dyt = ey[t] - sy;
                float rx = px[i] - sx;
                float ry = py[i] - sy;
                float det = dxt * dy2 - dx2 * dyt;
                float n1  = rx * dy2 - ry * dx2;
                float n2  = rx * dyt - ry * dxt;
                // sign-xor form: boolean-identical to
                //   det>0 ? (0<=n1<=det && 0<=n2<=det)
                //         : det<0 ? (det<=n1<=0 && det<=n2<=0) : false
                unsigned int sb = __float_as_uint(det) & 0x80000000u;
                float n1x = __uint_as_float(__float_as_uint(n1) ^ sb);
                float n2x = __uint_as_float(__float_as_uint(n2) ^ sb);
                float ad  = fabsf(det);
                bool hit = (n1x >= 0.0f) & (n1x <= ad) &
                           (n2x >= 0.0f) & (n2x <= ad) & (det != 0.0f);
                if (hit) cmask |= (1u << t);
            }
        }
    }

    // ---- wave64 reduce, cross-wave via LDS, one slot write per block ----
#pragma unroll
    for (int t = 0; t < TT; ++t) {
        float v = mind2[t];
        for (int o = 32; o; o >>= 1) v = fminf(v, __shfl_xor(v, o));
        mind2[t] = v;
    }
    for (int o = 32; o; o >>= 1) cmask |= __shfl_xor(cmask, o);

    if (lane == 0) {
#pragma unroll
        for (int t = 0; t < TT; ++t) sred[wave][t] = mind2[t];
        scmw[wave] = cmask;
    }
    __syncthreads();
    float* wfw = (float*)ws;
    if (tid < TT) {
        float v = sred[0][tid];
#pragma unroll
        for (int w2 = 1; w2 < NWAVE; ++w2) v = fminf(v, sred[w2][tid]);
        wfw[(tid * NSLOT + blk) * BB + b] = v;
    } else if (tid == 16) {
        unsigned int cm = 0;
#pragma unroll
        for (int w2 = 0; w2 < NWAVE; ++w2) cm |= scmw[w2];
        ws[OFF_CM + blk * BB + b] = cm;
    } else if (tid == 17) {
        ws[OFF_CNT + blk * BB + b] = (unsigned int)cnt;
    }

    // ---- ticket: release partials, last block runs the final stage ----
    // canonical threadFenceReduction pattern; device-scope fence + atomic
    // handles cross-XCD L2 visibility (G12/G16).
    __threadfence();                       // release (each storer flushes)
    __syncthreads();
    if (tid == 0) {
        unsigned int old = atomicAdd(&ws[OFF_CTR], 1u);
        slast = (old == (unsigned int)(NBLOCKS - 1));
    }
    __syncthreads();
    if (!slast) return;                    // block-uniform: no divergent syncs
    __threadfence();                       // acquire (invalidate stale caches)

    // ---- final stage (last block only, 512 threads; 8 waves) ----
    const float* wf = (const float*)ws;
    const int fb = tid & 63, g = tid >> 6;
    if (g < 6) {                           // g handles t = 2g, 2g+1
#pragma unroll
        for (int k = 0; k < 2; ++k) {
            const int t = 2 * g + k;
            float m = BIGF;
#pragma unroll
            for (int s = 0; s < NSLOT; ++s)
                m = fminf(m, wf[(t * NSLOT + s) * BB + fb]);
            smf[t * BB + fb] = m;
        }
    } else if (g == 6) {
        unsigned int cm = 0;
#pragma unroll
        for (int s = 0; s < NSLOT; ++s) cm |= ws[OFF_CM + s * BB + fb];
        scm[fb] = cm;
    } else {
        unsigned int has = 0;
#pragma unroll
        for (int s = 0; s < NSLOT; ++s) has |= ws[OFF_CNT + s * BB + fb];
        shas[fb] = has;
    }
    __syncthreads();

    if (tid < BB) {  // wave 0: thread = batch
        const bool hl = shas[fb] != 0;
        const unsigned int cm = scm[fb];
        const float4 mk0 = *reinterpret_cast<const float4*>(masks + fb * TT);
        const float4 mk1 = *reinterpret_cast<const float4*>(masks + fb * TT + 4);
        const float4 mk2 = *reinterpret_cast<const float4*>(masks + fb * TT + 8);
        const float mk[TT] = {mk0.x, mk0.y, mk0.z, mk0.w,
                              mk1.x, mk1.y, mk1.z, mk1.w,
                              mk2.x, mk2.y, mk2.z, mk2.w};
        float total = 0.0f, csum = 0.0f;
        bool blocked = false;
#pragma unroll
        for (int t = 0; t < TT; ++t) {
            bool valid_t = (mk[t] >= 0.5f) && hl;
            bool trig = valid_t && ((cm >> t) & 1u);
            blocked = blocked || trig;
            if (valid_t && !blocked) {
                float d = sqrtf(smf[t * BB + fb]);
                total += fmaxf(1.0f - d, 0.0f);
                csum += 1.0f;
            }
        }
        for (int o = 32; o; o >>= 1) {
            total += __shfl_xor(total, o);
            csum  += __shfl_xor(csum, o);
        }
        if (fb == 0) out[0] = (csum == 0.0f) ? 0.0f : total / fmaxf(csum, 1.0f);
    }
}

extern "C" void kernel_launch(void* const* d_in, const int* in_sizes, int n_in,
                              void* d_out, int out_size, void* d_ws, size_t ws_size,
                              hipStream_t stream) {
    const float* pred   = (const float*)d_in[0];
    const float* pts    = (const float*)d_in[1];
    const int*   labels = (const int*)d_in[2];
    const float* masks  = (const float*)d_in[3];
    float* out = (float*)d_out;
    unsigned int* ws = (unsigned int*)d_ws;

    // zero the ticket counter (ws is poisoned between iterations);
    // 4-byte memset node, graph-capturable, DMA path.
    hipMemsetAsync((char*)d_ws + OFF_CTR * sizeof(unsigned int), 0,
                   sizeof(unsigned int), stream);

    dim3 grid(NBLK, BB);
    gtmb_fused<<<grid, TPB, 0, stream>>>(pred, pts, labels, masks, ws, out);
}